// Round 2
// baseline (187.837 us; speedup 1.0000x reference)
//
#include <hip/hip_runtime.h>
#include <math.h>

// VIN forward on MI355X — single fused kernel (128 WGs x 512 thr, 8 px/thread).
// Sizes: N=128, H=W=64, CH_I=2, CH_H=150, CH_Q=10, N_ACT=8, VInum=36.
//
// R12 -> R13 change (K-loop sync only):
//  R12 counters: VALUBusy 25% == VALU issue floor (~0.68us/iter); LDS floor
//  ~0.7us/iter; wall ~2-2.7us/iter -> ~1.2-1.5us/iter is __syncthreads()
//  convoy (8-wave skew + full lgkmcnt drain) for a dependency that is only
//  1D nearest-neighbor: wave w owns rows 8w..8w+7; only boundary rows
//  8w/8w+7 cross waves, and only to waves w+-1. Replace the per-iter full
//  barrier with a per-wave LDS flag protocol: spin(flag[w+-1] >= it) ->
//  read -> compute -> write -> threadfence_block -> flag[w] = it+1.
//  RAW: neighbor boundary data ready <= flag >= it. WAR: buf[(it+1)&1]
//  boundary rows were read by neighbor at its iter it-1, which completed
//  before it set flag = it (reads precede writes in-iteration). Monotonic
//  flags on a 1D chain -> deadlock-free. Math untouched -> bit-identical.

typedef float v2f __attribute__((ext_vector_type(2)));

static __device__ __forceinline__ v2f splat2(float s) { v2f r; r.x = s; r.y = s; return r; }
static __device__ __forceinline__ v2f pkfma(v2f w, float v, v2f a) {
#if __has_builtin(__builtin_elementwise_fma)
    return __builtin_elementwise_fma(w, splat2(v), a);
#else
    v2f r; r.x = fmaf(w.x, v, a.x); r.y = fmaf(w.y, v, a.y); return r;
#endif
}
static __device__ __forceinline__ v2f pkmax(v2f a, v2f b) {
#if __has_builtin(__builtin_elementwise_max)
    return __builtin_elementwise_max(a, b);
#else
    v2f r; r.x = fmaxf(a.x, b.x); r.y = fmaxf(a.y, b.y); return r;
#endif
}

#define XROW 69
#define VROW 67
#define VSTR (66 * VROW)          // 4422 floats per v buffer

__global__ void
__attribute__((amdgpu_flat_work_group_size(512, 512)))
__attribute__((amdgpu_waves_per_eu(2, 2)))
vin_kernel(const float* __restrict__ x,
           const int* __restrict__ S1,
           const int* __restrict__ S2,
           const int* __restrict__ VInum,
           const float* __restrict__ w0,
           const float* __restrict__ b0,
           const float* __restrict__ w_r,
           const float* __restrict__ w_q,
           const float* __restrict__ w_sw,
           const float* __restrict__ w_sw2,
           const float* __restrict__ w_dense,
           float* __restrict__ out) {
    const int b = blockIdx.x;
    const int t = threadIdx.x;

    __shared__ float xs0[68 * XROW];     // x ch0, [y+2][x+2], 2-halo of zeros
    __shared__ float xs1[68 * XROW];     // x ch1
    __shared__ float rs[66 * VROW];      // r with 1-halo of zeros
    __shared__ float vpool[2 * VSTR];    // v double buffer, 1-halo of zeros
    __shared__ float wtA[1620];          // P chunk partials: 162 entries x 10
    __shared__ float Pp[450];            // P[d][e5x5][ci], zero-init (162 filled)
    __shared__ float Bt[90];             // bias chunk partials: 9 d x 10
    __shared__ float Bv[9];              // B[d] = w_r[d].b0
    __shared__ float W5c[459];           // 9 classes x (50 weights + bias)
    __shared__ v2f   swv2[45];           // w_sw v-part action-pairs: [d][ap]
    __shared__ float qsel[10];
    __shared__ int   wflag[8];           // per-wave completed-iteration count

    // ---- zero LDS (halos must be 0; Pp must be 0 for invalid combos) ----
    for (int i = t; i < 68 * XROW; i += 512) { xs0[i] = 0.f; xs1[i] = 0.f; }
    for (int i = t; i < 66 * VROW; i += 512) rs[i] = 0.f;
    for (int i = t; i < 2 * VSTR; i += 512) vpool[i] = 0.f;
    if (t < 450) Pp[t] = 0.f;
    if (t < 8) wflag[t] = 0;
    if (t < 45) {
        int d = t / 5, ap = t - d * 5;
        v2f w; w.x = w_sw[d * 20 + 10 + 2 * ap]; w.y = w_sw[d * 20 + 10 + 2 * ap + 1];
        swv2[t] = w;
    }
    __syncthreads();

    const int row = t >> 3;          // 0..63
    const int cb  = (t & 7) << 3;    // 0,8,...,56  (8 px per thread)

    // ---- stage x into split planes (16 contiguous floats = 4x float4) ----
    {
        const float* xb = x + (size_t)b * 64 * 64 * 2;
        const float4* xp = (const float4*)(xb + (row * 64 + cb) * 2);
        #pragma unroll
        for (int g = 0; g < 4; ++g) {
            float4 v4 = xp[g];
            int px = cb + g * 2;
            xs0[(row + 2) * XROW + px + 2] = v4.x;
            xs1[(row + 2) * XROW + px + 2] = v4.y;
            xs0[(row + 2) * XROW + px + 3] = v4.z;
            xs1[(row + 2) * XROW + px + 3] = v4.w;
        }
    }
    // ---- round A: P chunk partials (1620 items) + bias chunks (90) ----
    for (int idx = t; idx < 1620; idx += 512) {
        int entry = idx / 10, ch = idx - entry * 10;
        int d = entry / 18, rem = entry % 18;
        int uu = rem >> 1, ci = rem & 1;
        int c0 = ch * 15;
        const float* wr = w_r + d * 150;
        const float* wp = w0 + (uu * 2 + ci) * 150;
        float s = 0.f;
        for (int c = c0; c < c0 + 15; ++c) s += wr[c] * wp[c];
        wtA[idx] = s;
    }
    if (t < 90) {
        int d = t / 10, ch = t - d * 10, c0 = ch * 15;
        float s = 0.f;
        for (int c = c0; c < c0 + 15; ++c) s += w_r[d * 150 + c] * b0[c];
        Bt[t] = s;
    }
    __syncthreads();
    // ---- round B: reduce P entries (162) and B (9) ----
    if (t < 162) {
        float s = 0.f;
        #pragma unroll
        for (int i = 0; i < 10; ++i) s += wtA[t * 10 + i];
        int d = t / 18, rem = t % 18;
        int uu = rem >> 1, ci = rem & 1;
        int dy = d / 3 - 1, dx = d % 3 - 1;
        int uy = uu / 3 - 1, ux = uu % 3 - 1;
        int eidx = (dy + uy + 2) * 5 + (dx + ux + 2);
        Pp[d * 50 + eidx * 2 + ci] = s;
    } else if (t >= 256 && t < 265) {
        int d = t - 256;
        float s = 0.f;
        #pragma unroll
        for (int i = 0; i < 10; ++i) s += Bt[d * 10 + i];
        Bv[d] = s;
    }
    __syncthreads();
    // ---- round C: class subset-sums W5c[9][51] ----
    if (t < 459) {
        int cls = t / 51, j = t - cls * 51;
        int cy = cls / 3, cx = cls % 3;
        float s = 0.f;
        #pragma unroll
        for (int d = 0; d < 9; ++d) {
            int dy = d / 3 - 1, dx = d % 3 - 1;
            bool ok = (cy == 0 || (cy == 1 ? dy >= 0 : dy <= 0)) &&
                      (cx == 0 || (cx == 1 ? dx >= 0 : dx <= 0));
            if (ok) s += (j < 50) ? Pp[d * 50 + j] : Bv[d];
        }
        W5c[t] = s;
    }
    __syncthreads();

    // ---- r everywhere via class-weighted 5x5 stencil ----
    {
        int cy = (row == 0) ? 1 : (row == 63) ? 2 : 0;
        #pragma unroll
        for (int p = 0; p < 8; ++p) {
            int xx = cb + p;
            int cx = (xx == 0) ? 1 : (xx == 63) ? 2 : 0;
            const float* Wp = &W5c[(cy * 3 + cx) * 51];
            float acc = Wp[50];
            #pragma unroll
            for (int e = 0; e < 25; ++e) {
                int xi = (row + e / 5) * XROW + (xx + e % 5);
                acc = fmaf(xs0[xi], Wp[e * 2], acc);
                acc = fmaf(xs1[xi], Wp[e * 2 + 1], acc);
            }
            rs[(row + 1) * VROW + (xx + 1)] = acc;
        }
    }
    __syncthreads();

    const int K = VInum[0];

    // ---- Rsw precompute (packed action-pairs) + first step (w_q) ----
    v2f Rsw2[8][5];
    {
        float rwin[3][10];
        #pragma unroll
        for (int i = 0; i < 3; ++i) {
            const float* rp = &rs[(row + i) * VROW + cb];
            #pragma unroll
            for (int j = 0; j < 10; ++j) rwin[i][j] = rp[j];
        }
        float vmax[8];
        #pragma unroll
        for (int a = 0; a < 10; ++a) {
            #pragma unroll
            for (int p = 0; p < 8; ++p) {
                float accR = 0.f, accQ = 0.f;
                #pragma unroll
                for (int d = 0; d < 9; ++d) {
                    float rv = rwin[d / 3][p + d % 3];
                    accR = fmaf(w_sw[d * 20 + a], rv, accR);
                    accQ = fmaf(w_q[d * 20 + a],  rv, accQ);
                }
                if (a & 1) Rsw2[p][a >> 1].y = accR; else Rsw2[p][a >> 1].x = accR;
                vmax[p] = (a == 0) ? accQ : fmaxf(vmax[p], accQ);
            }
        }
        #pragma unroll
        for (int p = 0; p < 8; ++p)
            vpool[0 * VSTR + (row + 1) * VROW + (cb + p + 1)] = vmax[p];
    }
    __syncthreads();   // v_0 fully published; wflag[] == 0 for all waves

    // ---- hoist loop-invariant w_sw v-part weights into registers ----
    v2f wreg[45];
    #pragma unroll
    for (int i = 0; i < 45; ++i) wreg[i] = swv2[i];

    // ---- K-1 shared-weight VI steps: per-wave neighbor-flag sync ----
    // Wave w (t>>6) owns rows 8w..8w+7. Cross-wave deps: rows 8w-1 (wave
    // w-1) and 8w+8 (wave w+1) only. flag[w] = iterations completed.
    const int wv = t >> 6;
    volatile int* vf = wflag;
    int cur = 0;
    for (int it = 0; it < K - 1; ++it) {
        // acquire: neighbors must have published v_it (and finished reading
        // the buffer we are about to overwrite)
        if (wv > 0) { while (vf[wv - 1] < it) { } }
        if (wv < 7) { while (vf[wv + 1] < it) { } }
        asm volatile("" ::: "memory");
        __builtin_amdgcn_sched_barrier(0);

        const float* vb = &vpool[cur * VSTR + row * VROW + cb];
        float vwin[3][10];
        #pragma unroll
        for (int i = 0; i < 3; ++i)
            #pragma unroll
            for (int j = 0; j < 10; ++j) vwin[i][j] = vb[i * VROW + j];
        int nxt = cur ^ 1;
        v2f vmax2[8];
        #pragma unroll
        for (int ap = 0; ap < 5; ++ap) {
            v2f acc2[8];
            #pragma unroll
            for (int d = 0; d < 9; ++d) {
                v2f w2 = wreg[d * 5 + ap];   // register-resident
                #pragma unroll
                for (int p = 0; p < 8; ++p) {
                    float vv = vwin[d / 3][p + d % 3];
                    acc2[p] = (d == 0) ? pkfma(w2, vv, Rsw2[p][ap])
                                       : pkfma(w2, vv, acc2[p]);
                }
            }
            #pragma unroll
            for (int p = 0; p < 8; ++p)
                vmax2[p] = (ap == 0) ? acc2[p] : pkmax(vmax2[p], acc2[p]);
        }
        #pragma unroll
        for (int p = 0; p < 8; ++p)
            vpool[nxt * VSTR + (row + 1) * VROW + (cb + p + 1)] =
                fmaxf(vmax2[p].x, vmax2[p].y);

        // release: drain our ds_writes, then publish completion
        __threadfence_block();
        if ((t & 63) == 0) vf[wv] = it + 1;
        cur = nxt;
    }
    __syncthreads();   // final step reads cross-wave rows of v_{K-1}

    // ---- final step with w_sw2: q -> global, gather (S1,S2) ----
    const int s1 = S1[b], s2 = S2[b];
    {
        float rwin[3][10], vwin[3][10];
        #pragma unroll
        for (int i = 0; i < 3; ++i) {
            const float* rp = &rs[(row + i) * VROW + cb];
            const float* vb = &vpool[cur * VSTR + (row + i) * VROW + cb];
            #pragma unroll
            for (int j = 0; j < 10; ++j) { rwin[i][j] = rp[j]; vwin[i][j] = vb[j]; }
        }
        float qv[8][10];
        #pragma unroll
        for (int a = 0; a < 10; ++a) {
            #pragma unroll
            for (int p = 0; p < 8; ++p) {
                float acc = 0.f;
                #pragma unroll
                for (int d = 0; d < 9; ++d) {
                    acc = fmaf(w_sw2[d * 20 + a],      rwin[d / 3][p + d % 3], acc);
                    acc = fmaf(w_sw2[d * 20 + 10 + a], vwin[d / 3][p + d % 3], acc);
                }
                qv[p][a] = acc;
            }
        }
        // store q: 80 contiguous floats (8 px x 10 actions), 16B-aligned
        {
            float4* qp4 = (float4*)(out + 2048 + ((size_t)((b * 64 + row) * 64 + cb)) * 10);
            #pragma unroll
            for (int g = 0; g < 20; ++g)
                qp4[g] = make_float4(qv[(g * 4) / 10][(g * 4) % 10],
                                     qv[(g * 4 + 1) / 10][(g * 4 + 1) % 10],
                                     qv[(g * 4 + 2) / 10][(g * 4 + 2) % 10],
                                     qv[(g * 4 + 3) / 10][(g * 4 + 3) % 10]);
        }
        if (row == s1) {
            #pragma unroll
            for (int p = 0; p < 8; ++p)
                if (s2 == cb + p) {
                    #pragma unroll
                    for (int a = 0; a < 10; ++a) qsel[a] = qv[p][a];
                }
        }
    }
    __syncthreads();

    // ---- dense + softmax (thread 0), q_out (threads 0..9) ----
    if (t == 0) {
        float logits[8];
        float m = -1e30f;
        #pragma unroll
        for (int j = 0; j < 8; ++j) {
            float s = 0.f;
            #pragma unroll
            for (int a = 0; a < 10; ++a) s += qsel[a] * w_dense[a * 8 + j];
            logits[j] = s;
            m = fmaxf(m, s);
        }
        float sum = 0.f;
        float e[8];
        #pragma unroll
        for (int j = 0; j < 8; ++j) { e[j] = expf(logits[j] - m); sum += e[j]; }
        float inv = 1.f / sum;
        #pragma unroll
        for (int j = 0; j < 8; ++j) {
            out[b * 8 + j] = logits[j];
            out[1024 + b * 8 + j] = e[j] * inv;
        }
    }
    if (t < 10) out[5244928 + b * 10 + t] = qsel[t];
}

extern "C" void kernel_launch(void* const* d_in, const int* in_sizes, int n_in,
                              void* d_out, int out_size, void* d_ws, size_t ws_size,
                              hipStream_t stream) {
    const float* x      = (const float*)d_in[0];
    const int*   S1     = (const int*)d_in[1];
    const int*   S2     = (const int*)d_in[2];
    const int*   VInum  = (const int*)d_in[3];
    const float* w0     = (const float*)d_in[4];
    const float* b0     = (const float*)d_in[5];
    const float* w_r    = (const float*)d_in[6];
    const float* w_q    = (const float*)d_in[7];
    const float* w_sw   = (const float*)d_in[8];
    const float* w_sw2  = (const float*)d_in[9];
    const float* w_dense= (const float*)d_in[10];
    float* out = (float*)d_out;

    vin_kernel<<<128, 512, 0, stream>>>(x, S1, S2, VInum, w0, b0, w_r, w_q,
                                        w_sw, w_sw2, w_dense, out);
}

// Round 3
// 179.204 us; speedup vs baseline: 1.0482x; 1.0482x over previous
//
#include <hip/hip_runtime.h>
#include <math.h>

// VIN forward on MI355X — single fused kernel (128 WGs x 512 thr, 8 px/thread).
// Sizes: N=128, H=W=64, CH_I=2, CH_H=150, CH_Q=10, N_ACT=8, VInum=36.
//
// R13 -> R14 (K-loop body only; R13's flag sync REGRESSED -> barrier restored):
//  R12/R13 accounting: per iter all 8 waves issue 30 ds_reads in lockstep
//  after the barrier (LDS ~1560cyc, VALU idle), then all compute (~1720cyc,
//  LDS idle) -> phases alternate, ~1.37us/iter. Two coupled fixes:
//  (1) vprev[8]: center window row vwin[1][1..8] == own vmax from last
//      iter -> carry in registers; LDS reads 30 -> 22. Bit-identical.
//  (2) px-split pipeline: A = p0..3 (cols 0..5, 13 loads), B = p4..7
//      (cols 4..9, 9 loads). Issue A-loads then B-loads, compute A then B.
//      Fine-grained lgkmcnt lets compute-A start after 13 loads -> B loads
//      + other waves' loads complete under compute-A (pipes overlap).
//  Per-(ap,p) accumulation order unchanged (d=0..8) -> bit-identical.

typedef float v2f __attribute__((ext_vector_type(2)));

static __device__ __forceinline__ v2f splat2(float s) { v2f r; r.x = s; r.y = s; return r; }
static __device__ __forceinline__ v2f pkfma(v2f w, float v, v2f a) {
#if __has_builtin(__builtin_elementwise_fma)
    return __builtin_elementwise_fma(w, splat2(v), a);
#else
    v2f r; r.x = fmaf(w.x, v, a.x); r.y = fmaf(w.y, v, a.y); return r;
#endif
}
static __device__ __forceinline__ v2f pkmax(v2f a, v2f b) {
#if __has_builtin(__builtin_elementwise_max)
    return __builtin_elementwise_max(a, b);
#else
    v2f r; r.x = fmaxf(a.x, b.x); r.y = fmaxf(a.y, b.y); return r;
#endif
}

#define XROW 69
#define VROW 67
#define VSTR (66 * VROW)          // 4422 floats per v buffer

__global__ void
__attribute__((amdgpu_flat_work_group_size(512, 512)))
__attribute__((amdgpu_waves_per_eu(2, 2)))
vin_kernel(const float* __restrict__ x,
           const int* __restrict__ S1,
           const int* __restrict__ S2,
           const int* __restrict__ VInum,
           const float* __restrict__ w0,
           const float* __restrict__ b0,
           const float* __restrict__ w_r,
           const float* __restrict__ w_q,
           const float* __restrict__ w_sw,
           const float* __restrict__ w_sw2,
           const float* __restrict__ w_dense,
           float* __restrict__ out) {
    const int b = blockIdx.x;
    const int t = threadIdx.x;

    __shared__ float xs0[68 * XROW];     // x ch0, [y+2][x+2], 2-halo of zeros
    __shared__ float xs1[68 * XROW];     // x ch1
    __shared__ float rs[66 * VROW];      // r with 1-halo of zeros
    __shared__ float vpool[2 * VSTR];    // v double buffer, 1-halo of zeros
    __shared__ float wtA[1620];          // P chunk partials: 162 entries x 10
    __shared__ float Pp[450];            // P[d][e5x5][ci], zero-init (162 filled)
    __shared__ float Bt[90];             // bias chunk partials: 9 d x 10
    __shared__ float Bv[9];              // B[d] = w_r[d].b0
    __shared__ float W5c[459];           // 9 classes x (50 weights + bias)
    __shared__ v2f   swv2[45];           // w_sw v-part action-pairs: [d][ap]
    __shared__ float qsel[10];

    // ---- zero LDS (halos must be 0; Pp must be 0 for invalid combos) ----
    for (int i = t; i < 68 * XROW; i += 512) { xs0[i] = 0.f; xs1[i] = 0.f; }
    for (int i = t; i < 66 * VROW; i += 512) rs[i] = 0.f;
    for (int i = t; i < 2 * VSTR; i += 512) vpool[i] = 0.f;
    if (t < 450) Pp[t] = 0.f;
    if (t < 45) {
        int d = t / 5, ap = t - d * 5;
        v2f w; w.x = w_sw[d * 20 + 10 + 2 * ap]; w.y = w_sw[d * 20 + 10 + 2 * ap + 1];
        swv2[t] = w;
    }
    __syncthreads();

    const int row = t >> 3;          // 0..63
    const int cb  = (t & 7) << 3;    // 0,8,...,56  (8 px per thread)

    // ---- stage x into split planes (16 contiguous floats = 4x float4) ----
    {
        const float* xb = x + (size_t)b * 64 * 64 * 2;
        const float4* xp = (const float4*)(xb + (row * 64 + cb) * 2);
        #pragma unroll
        for (int g = 0; g < 4; ++g) {
            float4 v4 = xp[g];
            int px = cb + g * 2;
            xs0[(row + 2) * XROW + px + 2] = v4.x;
            xs1[(row + 2) * XROW + px + 2] = v4.y;
            xs0[(row + 2) * XROW + px + 3] = v4.z;
            xs1[(row + 2) * XROW + px + 3] = v4.w;
        }
    }
    // ---- round A: P chunk partials (1620 items) + bias chunks (90) ----
    for (int idx = t; idx < 1620; idx += 512) {
        int entry = idx / 10, ch = idx - entry * 10;
        int d = entry / 18, rem = entry % 18;
        int uu = rem >> 1, ci = rem & 1;
        int c0 = ch * 15;
        const float* wr = w_r + d * 150;
        const float* wp = w0 + (uu * 2 + ci) * 150;
        float s = 0.f;
        for (int c = c0; c < c0 + 15; ++c) s += wr[c] * wp[c];
        wtA[idx] = s;
    }
    if (t < 90) {
        int d = t / 10, ch = t - d * 10, c0 = ch * 15;
        float s = 0.f;
        for (int c = c0; c < c0 + 15; ++c) s += w_r[d * 150 + c] * b0[c];
        Bt[t] = s;
    }
    __syncthreads();
    // ---- round B: reduce P entries (162) and B (9) ----
    if (t < 162) {
        float s = 0.f;
        #pragma unroll
        for (int i = 0; i < 10; ++i) s += wtA[t * 10 + i];
        int d = t / 18, rem = t % 18;
        int uu = rem >> 1, ci = rem & 1;
        int dy = d / 3 - 1, dx = d % 3 - 1;
        int uy = uu / 3 - 1, ux = uu % 3 - 1;
        int eidx = (dy + uy + 2) * 5 + (dx + ux + 2);
        Pp[d * 50 + eidx * 2 + ci] = s;
    } else if (t >= 256 && t < 265) {
        int d = t - 256;
        float s = 0.f;
        #pragma unroll
        for (int i = 0; i < 10; ++i) s += Bt[d * 10 + i];
        Bv[d] = s;
    }
    __syncthreads();
    // ---- round C: class subset-sums W5c[9][51] ----
    if (t < 459) {
        int cls = t / 51, j = t - cls * 51;
        int cy = cls / 3, cx = cls % 3;
        float s = 0.f;
        #pragma unroll
        for (int d = 0; d < 9; ++d) {
            int dy = d / 3 - 1, dx = d % 3 - 1;
            bool ok = (cy == 0 || (cy == 1 ? dy >= 0 : dy <= 0)) &&
                      (cx == 0 || (cx == 1 ? dx >= 0 : dx <= 0));
            if (ok) s += (j < 50) ? Pp[d * 50 + j] : Bv[d];
        }
        W5c[t] = s;
    }
    __syncthreads();

    // ---- r everywhere via class-weighted 5x5 stencil ----
    {
        int cy = (row == 0) ? 1 : (row == 63) ? 2 : 0;
        #pragma unroll
        for (int p = 0; p < 8; ++p) {
            int xx = cb + p;
            int cx = (xx == 0) ? 1 : (xx == 63) ? 2 : 0;
            const float* Wp = &W5c[(cy * 3 + cx) * 51];
            float acc = Wp[50];
            #pragma unroll
            for (int e = 0; e < 25; ++e) {
                int xi = (row + e / 5) * XROW + (xx + e % 5);
                acc = fmaf(xs0[xi], Wp[e * 2], acc);
                acc = fmaf(xs1[xi], Wp[e * 2 + 1], acc);
            }
            rs[(row + 1) * VROW + (xx + 1)] = acc;
        }
    }
    __syncthreads();

    const int K = VInum[0];

    // ---- Rsw precompute (packed action-pairs) + first step (w_q) ----
    v2f Rsw2[8][5];
    float vprev[8];                  // own v values, carried across iterations
    {
        float rwin[3][10];
        #pragma unroll
        for (int i = 0; i < 3; ++i) {
            const float* rp = &rs[(row + i) * VROW + cb];
            #pragma unroll
            for (int j = 0; j < 10; ++j) rwin[i][j] = rp[j];
        }
        float vmax[8];
        #pragma unroll
        for (int a = 0; a < 10; ++a) {
            #pragma unroll
            for (int p = 0; p < 8; ++p) {
                float accR = 0.f, accQ = 0.f;
                #pragma unroll
                for (int d = 0; d < 9; ++d) {
                    float rv = rwin[d / 3][p + d % 3];
                    accR = fmaf(w_sw[d * 20 + a], rv, accR);
                    accQ = fmaf(w_q[d * 20 + a],  rv, accQ);
                }
                if (a & 1) Rsw2[p][a >> 1].y = accR; else Rsw2[p][a >> 1].x = accR;
                vmax[p] = (a == 0) ? accQ : fmaxf(vmax[p], accQ);
            }
        }
        #pragma unroll
        for (int p = 0; p < 8; ++p) {
            vpool[0 * VSTR + (row + 1) * VROW + (cb + p + 1)] = vmax[p];
            vprev[p] = vmax[p];
        }
    }
    __syncthreads();

    // ---- hoist loop-invariant w_sw v-part weights into registers ----
    v2f wreg[45];
    #pragma unroll
    for (int i = 0; i < 45; ++i) wreg[i] = swv2[i];

    // ---- K-1 shared-weight VI steps: pipelined px-split, reg center row ----
    int cur = 0;
    for (int it = 0; it < K - 1; ++it) {
        const float* vb = &vpool[cur * VSTR + row * VROW + cb];
        // A-loads: rows above/below, cols 0..5, + center-left edge (13)
        float v0[10], v2[10];
        #pragma unroll
        for (int j = 0; j < 6; ++j) v0[j] = vb[j];
        #pragma unroll
        for (int j = 0; j < 6; ++j) v2[j] = vb[2 * VROW + j];
        float vEL = vb[VROW];
        // B-loads: cols 6..9 + center-right edge (9)
        #pragma unroll
        for (int j = 6; j < 10; ++j) v0[j] = vb[j];
        #pragma unroll
        for (int j = 6; j < 10; ++j) v2[j] = vb[2 * VROW + j];
        float vER = vb[VROW + 9];
        // center row: edges from LDS, interior from registers (bit-identical)
        float v1[10];
        v1[0] = vEL; v1[9] = vER;
        #pragma unroll
        for (int j = 0; j < 8; ++j) v1[j + 1] = vprev[j];

        int nxt = cur ^ 1;
        // ---- block A: p = 0..3 (cols 0..5) ----
        v2f vmaxA[4];
        #pragma unroll
        for (int ap = 0; ap < 5; ++ap) {
            v2f acc[4];
            #pragma unroll
            for (int d = 0; d < 9; ++d) {
                v2f w2 = wreg[d * 5 + ap];
                const float* vr = (d < 3) ? v0 : (d < 6) ? v1 : v2;
                #pragma unroll
                for (int p = 0; p < 4; ++p) {
                    float vv = vr[p + d % 3];
                    acc[p] = (d == 0) ? pkfma(w2, vv, Rsw2[p][ap])
                                      : pkfma(w2, vv, acc[p]);
                }
            }
            #pragma unroll
            for (int p = 0; p < 4; ++p)
                vmaxA[p] = (ap == 0) ? acc[p] : pkmax(vmaxA[p], acc[p]);
        }
        // ---- block B: p = 4..7 (cols 4..9) ----
        v2f vmaxB[4];
        #pragma unroll
        for (int ap = 0; ap < 5; ++ap) {
            v2f acc[4];
            #pragma unroll
            for (int d = 0; d < 9; ++d) {
                v2f w2 = wreg[d * 5 + ap];
                const float* vr = (d < 3) ? v0 : (d < 6) ? v1 : v2;
                #pragma unroll
                for (int p = 0; p < 4; ++p) {
                    float vv = vr[p + 4 + d % 3];
                    acc[p] = (d == 0) ? pkfma(w2, vv, Rsw2[p + 4][ap])
                                      : pkfma(w2, vv, acc[p]);
                }
            }
            #pragma unroll
            for (int p = 0; p < 4; ++p)
                vmaxB[p] = (ap == 0) ? acc[p] : pkmax(vmaxB[p], acc[p]);
        }
        // ---- reduce pairs, publish, carry ----
        float* vw = &vpool[nxt * VSTR + (row + 1) * VROW + cb + 1];
        #pragma unroll
        for (int p = 0; p < 4; ++p) {
            float vn = fmaxf(vmaxA[p].x, vmaxA[p].y);
            vw[p] = vn; vprev[p] = vn;
        }
        #pragma unroll
        for (int p = 0; p < 4; ++p) {
            float vn = fmaxf(vmaxB[p].x, vmaxB[p].y);
            vw[p + 4] = vn; vprev[p + 4] = vn;
        }
        cur = nxt;
        __syncthreads();
    }

    // ---- final step with w_sw2: q -> global, gather (S1,S2) ----
    const int s1 = S1[b], s2 = S2[b];
    {
        float rwin[3][10], vwin[3][10];
        #pragma unroll
        for (int i = 0; i < 3; ++i) {
            const float* rp = &rs[(row + i) * VROW + cb];
            #pragma unroll
            for (int j = 0; j < 10; ++j) rwin[i][j] = rp[j];
        }
        const float* vb = &vpool[cur * VSTR + row * VROW + cb];
        #pragma unroll
        for (int j = 0; j < 10; ++j) vwin[0][j] = vb[j];
        #pragma unroll
        for (int j = 0; j < 10; ++j) vwin[2][j] = vb[2 * VROW + j];
        vwin[1][0] = vb[VROW]; vwin[1][9] = vb[VROW + 9];
        #pragma unroll
        for (int j = 0; j < 8; ++j) vwin[1][j + 1] = vprev[j];

        float qv[8][10];
        #pragma unroll
        for (int a = 0; a < 10; ++a) {
            #pragma unroll
            for (int p = 0; p < 8; ++p) {
                float acc = 0.f;
                #pragma unroll
                for (int d = 0; d < 9; ++d) {
                    acc = fmaf(w_sw2[d * 20 + a],      rwin[d / 3][p + d % 3], acc);
                    acc = fmaf(w_sw2[d * 20 + 10 + a], vwin[d / 3][p + d % 3], acc);
                }
                qv[p][a] = acc;
            }
        }
        // store q: 80 contiguous floats (8 px x 10 actions), 16B-aligned
        {
            float4* qp4 = (float4*)(out + 2048 + ((size_t)((b * 64 + row) * 64 + cb)) * 10);
            #pragma unroll
            for (int g = 0; g < 20; ++g)
                qp4[g] = make_float4(qv[(g * 4) / 10][(g * 4) % 10],
                                     qv[(g * 4 + 1) / 10][(g * 4 + 1) % 10],
                                     qv[(g * 4 + 2) / 10][(g * 4 + 2) % 10],
                                     qv[(g * 4 + 3) / 10][(g * 4 + 3) % 10]);
        }
        if (row == s1) {
            #pragma unroll
            for (int p = 0; p < 8; ++p)
                if (s2 == cb + p) {
                    #pragma unroll
                    for (int a = 0; a < 10; ++a) qsel[a] = qv[p][a];
                }
        }
    }
    __syncthreads();

    // ---- dense + softmax (thread 0), q_out (threads 0..9) ----
    if (t == 0) {
        float logits[8];
        float m = -1e30f;
        #pragma unroll
        for (int j = 0; j < 8; ++j) {
            float s = 0.f;
            #pragma unroll
            for (int a = 0; a < 10; ++a) s += qsel[a] * w_dense[a * 8 + j];
            logits[j] = s;
            m = fmaxf(m, s);
        }
        float sum = 0.f;
        float e[8];
        #pragma unroll
        for (int j = 0; j < 8; ++j) { e[j] = expf(logits[j] - m); sum += e[j]; }
        float inv = 1.f / sum;
        #pragma unroll
        for (int j = 0; j < 8; ++j) {
            out[b * 8 + j] = logits[j];
            out[1024 + b * 8 + j] = e[j] * inv;
        }
    }
    if (t < 10) out[5244928 + b * 10 + t] = qsel[t];
}

extern "C" void kernel_launch(void* const* d_in, const int* in_sizes, int n_in,
                              void* d_out, int out_size, void* d_ws, size_t ws_size,
                              hipStream_t stream) {
    const float* x      = (const float*)d_in[0];
    const int*   S1     = (const int*)d_in[1];
    const int*   S2     = (const int*)d_in[2];
    const int*   VInum  = (const int*)d_in[3];
    const float* w0     = (const float*)d_in[4];
    const float* b0     = (const float*)d_in[5];
    const float* w_r    = (const float*)d_in[6];
    const float* w_q    = (const float*)d_in[7];
    const float* w_sw   = (const float*)d_in[8];
    const float* w_sw2  = (const float*)d_in[9];
    const float* w_dense= (const float*)d_in[10];
    float* out = (float*)d_out;

    vin_kernel<<<128, 512, 0, stream>>>(x, S1, S2, VInum, w0, b0, w_r, w_q,
                                        w_sw, w_sw2, w_dense, out);
}